// Round 1
// baseline (377.537 us; speedup 1.0000x reference)
//
#include <hip/hip_runtime.h>
#include <cstdint>

// AttentionFlow (BiDAF-style) — fp32 baseline.
// B=8, c_len T=2048, q_len I=512, D=512. Output (B,T,4D) fp32.
//
// Pipeline:
//  1. rowdot:       sc[b,t] = <c,w_c>+b_c ; sq[b,i] = <q,w_q>+b_q       (ws)
//  2. s_gemm (NT):  S[b,t,i] = sc+sq+b_cq + <c*w_cq, q>  -> out[...,3D:4D]
//  3. softmax_i:    a = softmax_i(S) in place; mrow[b,t]=max_i S        (ws)
//  4. pv_gemm (NN): c2q = a @ q -> out[...,D:2D]
//  5. t_softmax:    bw[b,t] = softmax_t(mrow)                           (ws)
//  6. q2c split-K:  q2c[b,d] = sum_t bw*c  (partials + reduce)          (ws)
//  7. assemble:     out = [c | c2q | c*c2q | c*q2c]  (overwrites S slot last)

constexpr int kB = 8;
constexpr int kT = 2048;
constexpr int kI = 512;
constexpr int kD = 512;
constexpr int kW = 4 * kD;      // 2048 output row width

constexpr int BM = 64, BN = 64, BK = 32;
constexpr int kSplit = 16;
constexpr int kTchunk = kT / kSplit;   // 128

__device__ __forceinline__ float wave_max(float v) {
#pragma unroll
  for (int off = 32; off > 0; off >>= 1) v = fmaxf(v, __shfl_xor(v, off, 64));
  return v;
}
__device__ __forceinline__ float wave_sum(float v) {
#pragma unroll
  for (int off = 32; off > 0; off >>= 1) v += __shfl_xor(v, off, 64);
  return v;
}

// one wave per row; nrows must be divisible by 4 (blocks of 256 = 4 waves)
__global__ __launch_bounds__(256) void rowdot_kernel(
    const float* __restrict__ x, const float* __restrict__ w,
    const float* __restrict__ bias, float* __restrict__ out) {
  const int wave = (blockIdx.x * 256 + threadIdx.x) >> 6;
  const int lane = threadIdx.x & 63;
  const float* row = x + (size_t)wave * kD;
  float s = 0.f;
#pragma unroll
  for (int j = 0; j < kD / 64; ++j) s += row[lane + j * 64] * w[lane + j * 64];
  s = wave_sum(s);
  if (lane == 0) out[wave] = s + bias[0];
}

// S = (c .* w_cq) @ q^T + sc + sq + b_cq   -> out[...,3D:4D]
__global__ __launch_bounds__(256) void s_gemm_kernel(
    const float* __restrict__ c, const float* __restrict__ q,
    const float* __restrict__ w_cq, const float* __restrict__ b_cq,
    const float* __restrict__ sc, const float* __restrict__ sq,
    float* __restrict__ out) {
  __shared__ float As[BK][BM + 1];
  __shared__ float Bs[BK][BN + 1];
  const int b = blockIdx.z;
  const int t0 = blockIdx.x * BM;
  const int i0 = blockIdx.y * BN;
  const int tid = threadIdx.x;
  const int tm = tid & 15, tn = tid >> 4;
  const float* Cb = c + ((size_t)b * kT + t0) * kD;
  const float* Qb = q + ((size_t)b * kI + i0) * kD;
  float acc[4][4] = {};
  for (int k0 = 0; k0 < kD; k0 += BK) {
#pragma unroll
    for (int l = tid; l < BM * BK / 4; l += 256) {
      const int m = l >> 3;
      const int d4 = (l & 7) * 4;
      float4 v = *reinterpret_cast<const float4*>(Cb + (size_t)m * kD + k0 + d4);
      float4 wv = *reinterpret_cast<const float4*>(w_cq + k0 + d4);
      As[d4 + 0][m] = v.x * wv.x;
      As[d4 + 1][m] = v.y * wv.y;
      As[d4 + 2][m] = v.z * wv.z;
      As[d4 + 3][m] = v.w * wv.w;
      float4 u = *reinterpret_cast<const float4*>(Qb + (size_t)m * kD + k0 + d4);
      Bs[d4 + 0][m] = u.x;
      Bs[d4 + 1][m] = u.y;
      Bs[d4 + 2][m] = u.z;
      Bs[d4 + 3][m] = u.w;
    }
    __syncthreads();
#pragma unroll
    for (int k = 0; k < BK; ++k) {
      float av[4], bv[4];
#pragma unroll
      for (int r = 0; r < 4; ++r) av[r] = As[k][tm * 4 + r];
#pragma unroll
      for (int cc = 0; cc < 4; ++cc) bv[cc] = Bs[k][tn * 4 + cc];
#pragma unroll
      for (int r = 0; r < 4; ++r)
#pragma unroll
        for (int cc = 0; cc < 4; ++cc) acc[r][cc] += av[r] * bv[cc];
    }
    __syncthreads();
  }
  const float bq = b_cq[0];
#pragma unroll
  for (int r = 0; r < 4; ++r) {
    const int t = t0 + tm * 4 + r;
    const float scv = sc[b * kT + t] + bq;
    float4 o;
    o.x = acc[r][0] + scv + sq[b * kI + i0 + tn * 4 + 0];
    o.y = acc[r][1] + scv + sq[b * kI + i0 + tn * 4 + 1];
    o.z = acc[r][2] + scv + sq[b * kI + i0 + tn * 4 + 2];
    o.w = acc[r][3] + scv + sq[b * kI + i0 + tn * 4 + 3];
    *reinterpret_cast<float4*>(out + ((size_t)b * kT + t) * kW + 3 * kD + i0 + tn * 4) = o;
  }
}

// softmax over i (512) in place on out[...,3D:4D]; stores row max to mrow
__global__ __launch_bounds__(256) void softmax_i_kernel(
    float* __restrict__ out, float* __restrict__ mrow) {
  const int row = blockIdx.x;  // b*kT + t
  float* s = out + (size_t)row * kW + 3 * kD;
  const int tid = threadIdx.x;
  const float v0 = s[tid], v1 = s[tid + 256];
  __shared__ float redm[4];
  __shared__ float reds[4];
  const int wave = tid >> 6, lane = tid & 63;
  float mx = wave_max(fmaxf(v0, v1));
  if (lane == 0) redm[wave] = mx;
  __syncthreads();
  mx = fmaxf(fmaxf(redm[0], redm[1]), fmaxf(redm[2], redm[3]));
  const float e0 = __expf(v0 - mx), e1 = __expf(v1 - mx);
  float sm = wave_sum(e0 + e1);
  if (lane == 0) reds[wave] = sm;
  __syncthreads();
  sm = reds[0] + reds[1] + reds[2] + reds[3];
  const float inv = 1.f / sm;
  s[tid] = e0 * inv;
  s[tid + 256] = e1 * inv;
  if (tid == 0) mrow[row] = mx;
}

// c2q = a @ q   (a read from out[...,3D:4D], write out[...,D:2D])
__global__ __launch_bounds__(256) void pv_gemm_kernel(
    const float* __restrict__ q, float* __restrict__ out) {
  __shared__ float As[BK][BM + 1];
  __shared__ float Bs[BK][BN + 4];
  const int b = blockIdx.z;
  const int t0 = blockIdx.x * BM;
  const int d0 = blockIdx.y * BN;
  const int tid = threadIdx.x;
  const int tm = tid & 15, tn = tid >> 4;
  const float* Ab = out + ((size_t)b * kT + t0) * kW + 3 * kD;
  const float* Qb = q + (size_t)b * kI * kD;
  float acc[4][4] = {};
  for (int k0 = 0; k0 < kI; k0 += BK) {
#pragma unroll
    for (int l = tid; l < BM * BK / 4; l += 256) {
      const int m = l >> 3;
      const int d4 = (l & 7) * 4;
      float4 v = *reinterpret_cast<const float4*>(Ab + (size_t)m * kW + k0 + d4);
      As[d4 + 0][m] = v.x;
      As[d4 + 1][m] = v.y;
      As[d4 + 2][m] = v.z;
      As[d4 + 3][m] = v.w;
    }
#pragma unroll
    for (int l = tid; l < BK * BN / 4; l += 256) {
      const int kk = l >> 4;
      const int n4 = (l & 15) * 4;
      float4 u = *reinterpret_cast<const float4*>(Qb + (size_t)(k0 + kk) * kD + d0 + n4);
      Bs[kk][n4 + 0] = u.x;
      Bs[kk][n4 + 1] = u.y;
      Bs[kk][n4 + 2] = u.z;
      Bs[kk][n4 + 3] = u.w;
    }
    __syncthreads();
#pragma unroll
    for (int k = 0; k < BK; ++k) {
      float av[4], bv[4];
#pragma unroll
      for (int r = 0; r < 4; ++r) av[r] = As[k][tm * 4 + r];
#pragma unroll
      for (int cc = 0; cc < 4; ++cc) bv[cc] = Bs[k][tn * 4 + cc];
#pragma unroll
      for (int r = 0; r < 4; ++r)
#pragma unroll
        for (int cc = 0; cc < 4; ++cc) acc[r][cc] += av[r] * bv[cc];
    }
    __syncthreads();
  }
#pragma unroll
  for (int r = 0; r < 4; ++r) {
    float4 o = {acc[r][0], acc[r][1], acc[r][2], acc[r][3]};
    *reinterpret_cast<float4*>(
        out + ((size_t)b * kT + t0 + tm * 4 + r) * kW + kD + d0 + tn * 4) = o;
  }
}

// bw = softmax over t (2048) of mrow, per batch
__global__ __launch_bounds__(1024) void t_softmax_kernel(
    const float* __restrict__ mrow, float* __restrict__ bw) {
  const int b = blockIdx.x;
  const int tid = threadIdx.x;
  const float v0 = mrow[b * kT + tid], v1 = mrow[b * kT + tid + 1024];
  __shared__ float redm[16];
  __shared__ float reds[16];
  const int wave = tid >> 6, lane = tid & 63;
  float mx = wave_max(fmaxf(v0, v1));
  if (lane == 0) redm[wave] = mx;
  __syncthreads();
  mx = redm[0];
#pragma unroll
  for (int i = 1; i < 16; ++i) mx = fmaxf(mx, redm[i]);
  const float e0 = __expf(v0 - mx), e1 = __expf(v1 - mx);
  float sm = wave_sum(e0 + e1);
  if (lane == 0) reds[wave] = sm;
  __syncthreads();
  sm = 0.f;
#pragma unroll
  for (int i = 0; i < 16; ++i) sm += reds[i];
  const float inv = 1.f / sm;
  bw[b * kT + tid] = e0 * inv;
  bw[b * kT + tid + 1024] = e1 * inv;
}

// partial q2c over t-chunks (deterministic split-K, no atomics)
__global__ __launch_bounds__(256) void q2c_part_kernel(
    const float* __restrict__ c, const float* __restrict__ bw,
    float* __restrict__ part) {
  const int b = blockIdx.y;
  const int sp = blockIdx.x;
  const int tid = threadIdx.x;
  const int d0 = tid, d1 = tid + 256;
  float a0 = 0.f, a1 = 0.f;
  const int tbase = sp * kTchunk;
  for (int t = 0; t < kTchunk; ++t) {
    const float w = bw[b * kT + tbase + t];
    const float* crow = c + ((size_t)b * kT + tbase + t) * kD;
    a0 += w * crow[d0];
    a1 += w * crow[d1];
  }
  part[((size_t)b * kSplit + sp) * kD + d0] = a0;
  part[((size_t)b * kSplit + sp) * kD + d1] = a1;
}

__global__ __launch_bounds__(512) void q2c_reduce_kernel(
    const float* __restrict__ part, float* __restrict__ q2c) {
  const int b = blockIdx.x;
  const int d = threadIdx.x;
  float s = 0.f;
#pragma unroll
  for (int p = 0; p < kSplit; ++p) s += part[((size_t)b * kSplit + p) * kD + d];
  q2c[b * kD + d] = s;
}

// out = [c | c2q | c*c2q | c*q2c]; overwrites the S/a scratch slice last
__global__ __launch_bounds__(128) void assemble_kernel(
    const float* __restrict__ c, const float* __restrict__ q2c,
    float* __restrict__ out) {
  const int row = blockIdx.x;  // b*kT + t
  const int b = row >> 11;     // kT = 2048
  const int x4 = threadIdx.x * 4;
  const float4 cv = *reinterpret_cast<const float4*>(c + (size_t)row * kD + x4);
  float* orow = out + (size_t)row * kW;
  const float4 pv = *reinterpret_cast<const float4*>(orow + kD + x4);
  const float4 qc = *reinterpret_cast<const float4*>(q2c + b * kD + x4);
  *reinterpret_cast<float4*>(orow + x4) = cv;
  float4 m1{cv.x * pv.x, cv.y * pv.y, cv.z * pv.z, cv.w * pv.w};
  *reinterpret_cast<float4*>(orow + 2 * kD + x4) = m1;
  float4 m2{cv.x * qc.x, cv.y * qc.y, cv.z * qc.z, cv.w * qc.w};
  *reinterpret_cast<float4*>(orow + 3 * kD + x4) = m2;
}

extern "C" void kernel_launch(void* const* d_in, const int* in_sizes, int n_in,
                              void* d_out, int out_size, void* d_ws, size_t ws_size,
                              hipStream_t stream) {
  const float* c    = (const float*)d_in[0];
  const float* q    = (const float*)d_in[1];
  const float* w_c  = (const float*)d_in[2];
  const float* b_c  = (const float*)d_in[3];
  const float* w_q  = (const float*)d_in[4];
  const float* b_q  = (const float*)d_in[5];
  const float* w_cq = (const float*)d_in[6];
  const float* b_cq = (const float*)d_in[7];
  float* out = (float*)d_out;
  float* ws = (float*)d_ws;

  // ws layout (floats): sc 16384 | sq 4096 | mrow 16384 | bw 16384 |
  //                     part 65536 | q2c 4096   (~480 KB total)
  float* sc   = ws;
  float* sq   = sc + kB * kT;
  float* mrow = sq + kB * kI;
  float* bw   = mrow + kB * kT;
  float* part = bw + kB * kT;
  float* q2c  = part + (size_t)kB * kSplit * kD;

  rowdot_kernel<<<kB * kT / 4, 256, 0, stream>>>(c, w_c, b_c, sc);
  rowdot_kernel<<<kB * kI / 4, 256, 0, stream>>>(q, w_q, b_q, sq);

  dim3 gs(kT / BM, kI / BN, kB);
  s_gemm_kernel<<<gs, 256, 0, stream>>>(c, q, w_cq, b_cq, sc, sq, out);

  softmax_i_kernel<<<kB * kT, 256, 0, stream>>>(out, mrow);

  dim3 gp(kT / BM, kD / BN, kB);
  pv_gemm_kernel<<<gp, 256, 0, stream>>>(q, out);

  t_softmax_kernel<<<kB, 1024, 0, stream>>>(mrow, bw);
  dim3 gq(kSplit, kB);
  q2c_part_kernel<<<gq, 256, 0, stream>>>(c, bw, part);
  q2c_reduce_kernel<<<kB, 512, 0, stream>>>(part, q2c);

  assemble_kernel<<<kB * kT, 128, 0, stream>>>(c, q2c, out);
}

// Round 2
// 114.567 us; speedup vs baseline: 3.2953x; 3.2953x over previous
//
#include <hip/hip_runtime.h>
#include <cstdint>

// AttentionFlow — bf16 MFMA version.
// B=8, T=2048, I=512, D=512. Output (B,T,4D) fp32.
//
//  1. rowdot:        sc, sq                                    (ws)
//  2. s_gemm_mfma:   S = (c.*w_cq) @ q^T + biases -> out[...,3D:4D] (fp32)
//  3. softmax_pack:  a = softmax_i(S), packed bf16 into first 1KB of S slot;
//                    mrow = max_i S                            (ws)
//  4. t_softmax:     bw = softmax_t(mrow)                      (ws)
//  5. q2c:           q2c[b,d] = sum_t bw*c (split-K)           (ws)
//  6. pv_gemm_mfma:  c2q = a @ q ; epilogue writes out slots 0..2:
//                    [c | c2q | c*c2q | -]
//  7. slot3:         out[...,3D:4D] = c*q2c  (after pv: overwrites packed a)

constexpr int kB = 8;
constexpr int kT = 2048;
constexpr int kI = 512;
constexpr int kD = 512;
constexpr int kW = 4 * kD;

constexpr int kSplit = 16;
constexpr int kTchunk = kT / kSplit;

constexpr int LROW = 80;  // LDS row stride bytes: 32 bf16 (64B) + 16B pad

using f32x4  = __attribute__((ext_vector_type(4))) float;
using bf16x4 = __attribute__((ext_vector_type(4))) __bf16;
using bf16x8 = __attribute__((ext_vector_type(8))) __bf16;

__device__ __forceinline__ float wave_max(float v) {
#pragma unroll
  for (int off = 32; off > 0; off >>= 1) v = fmaxf(v, __shfl_xor(v, off, 64));
  return v;
}
__device__ __forceinline__ float wave_sum(float v) {
#pragma unroll
  for (int off = 32; off > 0; off >>= 1) v += __shfl_xor(v, off, 64);
  return v;
}

__global__ __launch_bounds__(256) void rowdot_kernel(
    const float* __restrict__ x, const float* __restrict__ w,
    const float* __restrict__ bias, float* __restrict__ out) {
  const int wave = (blockIdx.x * 256 + threadIdx.x) >> 6;
  const int lane = threadIdx.x & 63;
  const float* row = x + (size_t)wave * kD;
  float s = 0.f;
#pragma unroll
  for (int j = 0; j < kD / 64; ++j) s += row[lane + j * 64] * w[lane + j * 64];
  s = wave_sum(s);
  if (lane == 0) out[wave] = s + bias[0];
}

// ---------------- S = (c .* w_cq) @ q^T + sc + sq + b_cq ----------------
__global__ __launch_bounds__(256, 2) void s_gemm_mfma(
    const float* __restrict__ c, const float* __restrict__ q,
    const float* __restrict__ w_cq, const float* __restrict__ b_cq,
    const float* __restrict__ sc, const float* __restrict__ sq,
    float* __restrict__ out) {
  __shared__ __align__(16) char lA[128 * LROW];
  __shared__ __align__(16) char lB[128 * LROW];
  const int b = blockIdx.z;
  const int t0 = blockIdx.x * 128;
  const int i0 = blockIdx.y * 128;
  const int tid = threadIdx.x;
  const int lane = tid & 63;
  const int w = tid >> 6;
  const int wm = w >> 1, wn = w & 1;
  const int lr = lane & 15, lg = lane >> 4;

  const int srow = tid >> 3;      // staging row (0..31), +32 per j
  const int kq = (tid & 7) * 4;   // staging float4 column within BK=32
  const float* Cb = c + ((size_t)(b * kT + t0)) * kD;
  const float* Qb = q + ((size_t)(b * kI + i0)) * kD;

  f32x4 acc[4][4] = {};

  for (int k0 = 0; k0 < kD; k0 += 32) {
    const f32x4 wv = *(const f32x4*)(w_cq + k0 + kq);
    __syncthreads();
#pragma unroll
    for (int j = 0; j < 4; ++j) {
      const int row = srow + j * 32;
      f32x4 v = *(const f32x4*)(Cb + (size_t)row * kD + k0 + kq);
      f32x4 u = *(const f32x4*)(Qb + (size_t)row * kD + k0 + kq);
      f32x4 vw = v * wv;
      bf16x4 bv = {(__bf16)vw.x, (__bf16)vw.y, (__bf16)vw.z, (__bf16)vw.w};
      bf16x4 bu = {(__bf16)u.x, (__bf16)u.y, (__bf16)u.z, (__bf16)u.w};
      *(bf16x4*)(lA + row * LROW + kq * 2) = bv;
      *(bf16x4*)(lB + row * LROW + kq * 2) = bu;
    }
    __syncthreads();
    bf16x8 af[4], bfv[4];
#pragma unroll
    for (int m = 0; m < 4; ++m)
      af[m] = *(const bf16x8*)(lA + (wm * 64 + m * 16 + lr) * LROW + lg * 16);
#pragma unroll
    for (int n = 0; n < 4; ++n)
      bfv[n] = *(const bf16x8*)(lB + (wn * 64 + n * 16 + lr) * LROW + lg * 16);
#pragma unroll
    for (int m = 0; m < 4; ++m)
#pragma unroll
      for (int n = 0; n < 4; ++n)
        acc[m][n] = __builtin_amdgcn_mfma_f32_16x16x32_bf16(
            af[m], bfv[n], acc[m][n], 0, 0, 0);
  }

  const float bq = b_cq[0];
  float sqv[4];
#pragma unroll
  for (int n = 0; n < 4; ++n)
    sqv[n] = sq[b * kI + i0 + wn * 64 + n * 16 + lr];
#pragma unroll
  for (int m = 0; m < 4; ++m) {
#pragma unroll
    for (int r = 0; r < 4; ++r) {
      const int t = t0 + wm * 64 + m * 16 + lg * 4 + r;
      const float scv = sc[b * kT + t] + bq;
      float* orow = out + ((size_t)(b * kT + t)) * kW + 3 * kD + i0 + wn * 64;
#pragma unroll
      for (int n = 0; n < 4; ++n)
        orow[n * 16 + lr] = acc[m][n][r] + scv + sqv[n];
    }
  }
}

// ---- softmax over i (512) on S; pack a as bf16 into first 1KB of slot ----
__global__ __launch_bounds__(256) void softmax_pack(
    float* __restrict__ out, float* __restrict__ mrow) {
  const int row = blockIdx.x;  // b*kT + t
  float* s = out + (size_t)row * kW + 3 * kD;
  const int tid = threadIdx.x;
  const float v0 = s[tid], v1 = s[tid + 256];
  __shared__ float redm[4];
  __shared__ float reds[4];
  const int wave = tid >> 6, lane = tid & 63;
  float mx = wave_max(fmaxf(v0, v1));
  if (lane == 0) redm[wave] = mx;
  __syncthreads();
  mx = fmaxf(fmaxf(redm[0], redm[1]), fmaxf(redm[2], redm[3]));
  const float e0 = __expf(v0 - mx), e1 = __expf(v1 - mx);
  float sm = wave_sum(e0 + e1);
  if (lane == 0) reds[wave] = sm;
  __syncthreads();
  sm = reds[0] + reds[1] + reds[2] + reds[3];
  const float inv = 1.f / sm;
  __bf16* a = (__bf16*)s;
  a[tid] = (__bf16)(e0 * inv);
  a[tid + 256] = (__bf16)(e1 * inv);
  if (tid == 0) mrow[row] = mx;
}

__global__ __launch_bounds__(1024) void t_softmax_kernel(
    const float* __restrict__ mrow, float* __restrict__ bw) {
  const int b = blockIdx.x;
  const int tid = threadIdx.x;
  const float v0 = mrow[b * kT + tid], v1 = mrow[b * kT + tid + 1024];
  __shared__ float redm[16];
  __shared__ float reds[16];
  const int wave = tid >> 6, lane = tid & 63;
  float mx = wave_max(fmaxf(v0, v1));
  if (lane == 0) redm[wave] = mx;
  __syncthreads();
  mx = redm[0];
#pragma unroll
  for (int i = 1; i < 16; ++i) mx = fmaxf(mx, redm[i]);
  const float e0 = __expf(v0 - mx), e1 = __expf(v1 - mx);
  float sm = wave_sum(e0 + e1);
  if (lane == 0) reds[wave] = sm;
  __syncthreads();
  sm = 0.f;
#pragma unroll
  for (int i = 0; i < 16; ++i) sm += reds[i];
  const float inv = 1.f / sm;
  bw[b * kT + tid] = e0 * inv;
  bw[b * kT + tid + 1024] = e1 * inv;
}

__global__ __launch_bounds__(256) void q2c_part_kernel(
    const float* __restrict__ c, const float* __restrict__ bw,
    float* __restrict__ part) {
  const int b = blockIdx.y;
  const int sp = blockIdx.x;
  const int tid = threadIdx.x;
  const int d0 = tid, d1 = tid + 256;
  float a0 = 0.f, a1 = 0.f;
  const int tbase = sp * kTchunk;
  for (int t = 0; t < kTchunk; ++t) {
    const float w = bw[b * kT + tbase + t];
    const float* crow = c + ((size_t)b * kT + tbase + t) * kD;
    a0 += w * crow[d0];
    a1 += w * crow[d1];
  }
  part[((size_t)b * kSplit + sp) * kD + d0] = a0;
  part[((size_t)b * kSplit + sp) * kD + d1] = a1;
}

__global__ __launch_bounds__(512) void q2c_reduce_kernel(
    const float* __restrict__ part, float* __restrict__ q2c) {
  const int b = blockIdx.x;
  const int d = threadIdx.x;
  float s = 0.f;
#pragma unroll
  for (int p = 0; p < kSplit; ++p) s += part[((size_t)b * kSplit + p) * kD + d];
  q2c[b * kD + d] = s;
}

// --------- c2q = a @ q ; fused epilogue writes slots [c | c2q | c*c2q] ----
__global__ __launch_bounds__(256, 2) void pv_gemm_mfma(
    const float* __restrict__ c, const float* __restrict__ q,
    const float* __restrict__ q2c, float* __restrict__ out) {
  __shared__ __align__(16) char lA[128 * LROW];
  __shared__ __align__(16) char lB[128 * LROW];
  const int b = blockIdx.z;
  const int t0 = blockIdx.x * 128;
  const int d0 = blockIdx.y * 128;
  const int tid = threadIdx.x;
  const int lane = tid & 63;
  const int w = tid >> 6;
  const int wm = w >> 1, wn = w & 1;
  const int lr = lane & 15, lg = lane >> 4;

  // A: packed bf16 a in out[...,3D:3D+256 floats]; row stride kW*2 elements
  const int arow = tid >> 2;       // 0..63, +64 for s=1
  const int akc = (tid & 3) * 8;   // bf16 element offset within BK=32
  const __bf16* abase = (const __bf16*)out;

  // B: transpose-stage q (K=i rows, N=d cols) into lB[n][k]
  const int bk = (tid & 7) * 4;
  const int bn = (tid >> 3) * 4;
  const float* Qb = q + ((size_t)b * kI) * kD + d0 + bn;

  f32x4 acc[4][4] = {};

  for (int k0 = 0; k0 < kI; k0 += 32) {
    __syncthreads();
#pragma unroll
    for (int s = 0; s < 2; ++s) {
      const int row = arow + s * 64;
      const size_t ae = ((size_t)(b * kT + t0 + row)) * (kW * 2) + 3 * kD * 2 + k0 + akc;
      uint4 av = *(const uint4*)(abase + ae);
      *(uint4*)(lA + row * LROW + akc * 2) = av;
    }
    {
      f32x4 r0 = *(const f32x4*)(Qb + (size_t)(k0 + bk + 0) * kD);
      f32x4 r1 = *(const f32x4*)(Qb + (size_t)(k0 + bk + 1) * kD);
      f32x4 r2 = *(const f32x4*)(Qb + (size_t)(k0 + bk + 2) * kD);
      f32x4 r3 = *(const f32x4*)(Qb + (size_t)(k0 + bk + 3) * kD);
#pragma unroll
      for (int j = 0; j < 4; ++j) {
        bf16x4 bv = {(__bf16)r0[j], (__bf16)r1[j], (__bf16)r2[j], (__bf16)r3[j]};
        *(bf16x4*)(lB + (bn + j) * LROW + bk * 2) = bv;
      }
    }
    __syncthreads();
    bf16x8 af[4], bfv[4];
#pragma unroll
    for (int m = 0; m < 4; ++m)
      af[m] = *(const bf16x8*)(lA + (wm * 64 + m * 16 + lr) * LROW + lg * 16);
#pragma unroll
    for (int n = 0; n < 4; ++n)
      bfv[n] = *(const bf16x8*)(lB + (wn * 64 + n * 16 + lr) * LROW + lg * 16);
#pragma unroll
    for (int m = 0; m < 4; ++m)
#pragma unroll
      for (int n = 0; n < 4; ++n)
        acc[m][n] = __builtin_amdgcn_mfma_f32_16x16x32_bf16(
            af[m], bfv[n], acc[m][n], 0, 0, 0);
  }

#pragma unroll
  for (int m = 0; m < 4; ++m) {
#pragma unroll
    for (int r = 0; r < 4; ++r) {
      const int t = t0 + wm * 64 + m * 16 + lg * 4 + r;
      const size_t rbase = (size_t)(b * kT + t);
      const float* crow = c + rbase * kD + d0 + wn * 64;
      float* orow = out + rbase * kW;
#pragma unroll
      for (int n = 0; n < 4; ++n) {
        const int dl = n * 16 + lr;
        const int d = d0 + wn * 64 + dl;
        const float cv = crow[dl];
        const float pv = acc[m][n][r];
        orow[d] = cv;
        orow[kD + d] = pv;
        orow[2 * kD + d] = cv * pv;
      }
    }
  }
}

// ----------------- final: out[...,3D:4D] = c * q2c ------------------------
__global__ __launch_bounds__(128) void slot3_kernel(
    const float* __restrict__ c, const float* __restrict__ q2c,
    float* __restrict__ out) {
  const int row = blockIdx.x;  // b*kT + t
  const int b = row >> 11;
  const int x4 = threadIdx.x * 4;
  f32x4 cv = *(const f32x4*)(c + (size_t)row * kD + x4);
  f32x4 qc = *(const f32x4*)(q2c + b * kD + x4);
  *(f32x4*)(out + (size_t)row * kW + 3 * kD + x4) = cv * qc;
}

extern "C" void kernel_launch(void* const* d_in, const int* in_sizes, int n_in,
                              void* d_out, int out_size, void* d_ws, size_t ws_size,
                              hipStream_t stream) {
  const float* c    = (const float*)d_in[0];
  const float* q    = (const float*)d_in[1];
  const float* w_c  = (const float*)d_in[2];
  const float* b_c  = (const float*)d_in[3];
  const float* w_q  = (const float*)d_in[4];
  const float* b_q  = (const float*)d_in[5];
  const float* w_cq = (const float*)d_in[6];
  const float* b_cq = (const float*)d_in[7];
  float* out = (float*)d_out;
  float* ws = (float*)d_ws;

  // ws layout (floats): sc 16384 | sq 4096 | mrow 16384 | bw 16384 |
  //                     part 65536 | q2c 4096
  float* sc   = ws;
  float* sq   = sc + kB * kT;
  float* mrow = sq + kB * kI;
  float* bw   = mrow + kB * kT;
  float* part = bw + kB * kT;
  float* q2c  = part + (size_t)kB * kSplit * kD;

  rowdot_kernel<<<kB * kT / 4, 256, 0, stream>>>(c, w_c, b_c, sc);
  rowdot_kernel<<<kB * kI / 4, 256, 0, stream>>>(q, w_q, b_q, sq);

  dim3 gs(kT / 128, kI / 128, kB);
  s_gemm_mfma<<<gs, 256, 0, stream>>>(c, q, w_cq, b_cq, sc, sq, out);

  softmax_pack<<<kB * kT, 256, 0, stream>>>(out, mrow);

  t_softmax_kernel<<<kB, 1024, 0, stream>>>(mrow, bw);
  dim3 gq(kSplit, kB);
  q2c_part_kernel<<<gq, 256, 0, stream>>>(c, bw, part);
  q2c_reduce_kernel<<<kB, 512, 0, stream>>>(part, q2c);

  dim3 gp(kT / 128, kD / 128, kB);
  pv_gemm_mfma<<<gp, 256, 0, stream>>>(c, q, q2c, out);

  slot3_kernel<<<kB * kT, 128, 0, stream>>>(c, q2c, out);
}